// Round 21
// baseline (209.145 us; speedup 1.0000x reference)
//
#include <hip/hip_runtime.h>

typedef short  bf16x8 __attribute__((ext_vector_type(8)));
typedef float  f32x4  __attribute__((ext_vector_type(4)));

#define WROWS 22            // 16 output rows + 6 halo
#define WSTR  72            // ushorts per row (144 B)
#define WPAD  8             // lane63/jo3 b128 overrun pad (zeroed)
#define WSZ   (WROWS * WSTR + WPAD)
#define NCHW  18            // float4 chunks per row
#define CHTW  (WROWS * NCHW)          // 396 chunks per wave-tile

static __device__ __forceinline__ unsigned int rne16(float f) {
    unsigned int u = __float_as_uint(f);
    return (u + 0x7FFFu + ((u >> 16) & 1u)) >> 16;   // fp32 -> bf16 RNE
}

// trunc-pack two fp32 -> packed 2xbf16 (2 bit-ops; error < 1 ulp bf16)
static __device__ __forceinline__ unsigned int tpk(float lo, float hi) {
    return (__float_as_uint(hi) & 0xFFFF0000u) | (__float_as_uint(lo) >> 16);
}

// ---- Setup: banded-B fragments once into ws (7 dy x 64 lanes x 16B) ----
// B[u][j] = w[dy][u-j-1]; rows u=0 and u>=24 structurally zero.
__global__ void build_bfrag(const float* __restrict__ w, bf16x8* __restrict__ ws) {
    const int l   = threadIdx.x;      // 64 threads
    const int l15 = l & 15;
    const int u0  = (l >> 4) * 8;
#pragma unroll
    for (int dy = 0; dy < 7; ++dy) {
        union { unsigned int u[4]; bf16x8 v; } bb;
#pragma unroll
        for (int qp = 0; qp < 4; ++qp) {
            unsigned int half[2];
#pragma unroll
            for (int h = 0; h < 2; ++h) {
                const int d = u0 + qp * 2 + h - l15 - 1;     // weight col dx
                const float val = (d >= 0 && d < 7) ? w[dy * 7 + d] : 0.f;
                half[h] = rne16(val);
            }
            bb.u[qp] = half[0] | (half[1] << 16);
        }
        ws[dy * 64 + l] = bb.v;
    }
}

// ---- Main: interior waves read A-fragments DIRECTLY from global (no LDS,
// no monolithic vmcnt stall, L1 serves the 7x dy-overlap); edge waves use
// the proven R15 LDS staging path for padding semantics. ----
__global__ __launch_bounds__(256)
void conv7x7_mfma(const float* __restrict__ x, const bf16x8* __restrict__ Bws,
                  float* __restrict__ out) {
    __shared__ unsigned short lds[4][WSZ];   // 12736 B (edge path only)

    const int W = 512, H = 512;
    // XCD-aware bijective swizzle (8192 % 8 == 0)
    const int raw = blockIdx.x;
    const int bi  = (raw & 7) * 1024 + (raw >> 3);
    const int n   = bi >> 6;             // n(7) | ty(3) | tx(3)
    const int ty  = (bi >> 3) & 7;
    const int tx  = bi & 7;

    const float* xn = x + (size_t)n * (H * W);
    float*       on = out + (size_t)n * (H * W);

    const int t   = threadIdx.x;
    const int l   = t & 63;
    const int wv  = t >> 6;
    const int l15 = l & 15;
    const int lk  = l >> 4;
    const int u0  = lk * 8;

    const int y0 = ty * 64 + wv * 16;    // wave's output rows y0..y0+15
    const int x0 = tx * 64;              // wave's output cols x0..x0+63

    // Prebuilt B fragments (L2-resident broadcast)
    bf16x8 Bf[7];
#pragma unroll
    for (int dy = 0; dy < 7; ++dy) Bf[dy] = Bws[dy * 64 + l];

    const bool edge = (tx == 0) | (tx == 7) | (y0 == 0) | (y0 == 496);

    if (!edge) {
        // ---------- interior fast path: direct-from-global A ----------
        // Lane reads rows y0+l15+dy-3 (all in [13,501]), cols
        // x0-4+jo*16+u0..+7 (all in [60,459]) -> no boundary checks.
        const float* base = xn + (size_t)(y0 + l15 - 3) * W + (x0 - 4 + u0);
#pragma unroll 1
        for (int jo = 0; jo < 4; ++jo) {
            f32x4 acc = {0.f, 0.f, 0.f, 0.f};
            const float* pj = base + jo * 16;
#pragma unroll
            for (int dy = 0; dy < 7; ++dy) {
                const float* p = pj + (size_t)dy * W;
                const float4 lo = *reinterpret_cast<const float4*>(p);
                const float4 hi = *reinterpret_cast<const float4*>(p + 4);
                union { unsigned int u[4]; bf16x8 v; } pk;
                pk.u[0] = tpk(lo.x, lo.y);
                pk.u[1] = tpk(lo.z, lo.w);
                pk.u[2] = tpk(hi.x, hi.y);
                pk.u[3] = tpk(hi.z, hi.w);
                acc = __builtin_amdgcn_mfma_f32_16x16x32_bf16(pk.v, Bf[dy], acc,
                                                              0, 0, 0);
            }
#pragma unroll
            for (int rr = 0; rr < 4; ++rr) {
                const int gr = y0 + lk * 4 + rr;
                on[(size_t)gr * W + x0 + jo * 16 + l15] = acc[rr];
            }
        }
    } else {
        // ---------- edge path: R15 wave-private LDS staging (verbatim) ----------
        unsigned short* my = lds[wv];
        if (l < WPAD) my[WROWS * WSTR + l] = 0;   // zero wrap pad

        float4 sreg[7];
        int    loff[7];
        bool   act[7];
#pragma unroll
        for (int it = 0; it < 7; ++it) {
            const int idx = l + 64 * it;
            const int r   = idx / NCHW;
            const int cc  = idx - r * NCHW;
            const int gr  = y0 - 3 + r;
            const int gc  = x0 - 4 + 4 * cc;   // 16B-aligned, full-or-zero OOB
            act[it]  = (idx < CHTW);
            loff[it] = r * WSTR + 4 * cc;
            float4 v = make_float4(0.f, 0.f, 0.f, 0.f);
            if (act[it] && gr >= 0 && gr < H && gc >= 0 && gc <= W - 4)
                v = *reinterpret_cast<const float4*>(&xn[(size_t)gr * W + gc]);
            sreg[it] = v;
        }
#pragma unroll
        for (int it = 0; it < 7; ++it) {
            if (act[it]) {
                const unsigned p0 = rne16(sreg[it].x) | (rne16(sreg[it].y) << 16);
                const unsigned p1 = rne16(sreg[it].z) | (rne16(sreg[it].w) << 16);
                *reinterpret_cast<uint2*>(&my[loff[it]]) = make_uint2(p0, p1);
            }
        }
        // same-wave ds_write -> ds_read ordering via lgkmcnt; no barrier

#pragma unroll
        for (int jo = 0; jo < 4; ++jo) {
            f32x4 acc = {0.f, 0.f, 0.f, 0.f};
#pragma unroll
            for (int dy = 0; dy < 7; ++dy) {
                const int row = l15 + dy;
                const bf16x8 a = *reinterpret_cast<const bf16x8*>(
                    &my[row * WSTR + jo * 16 + u0]);
                acc = __builtin_amdgcn_mfma_f32_16x16x32_bf16(a, Bf[dy], acc,
                                                              0, 0, 0);
            }
#pragma unroll
            for (int rr = 0; rr < 4; ++rr) {
                const int gr = y0 + lk * 4 + rr;
                on[(size_t)gr * W + x0 + jo * 16 + l15] = acc[rr];
            }
        }
    }
}

extern "C" void kernel_launch(void* const* d_in, const int* in_sizes, int n_in,
                              void* d_out, int out_size, void* d_ws, size_t ws_size,
                              hipStream_t stream) {
    const float* x = (const float*)d_in[0];
    const float* w = (const float*)d_in[1];
    float* out = (float*)d_out;
    bf16x8* bws = (bf16x8*)d_ws;

    build_bfrag<<<1, 64, 0, stream>>>(w, bws);

    const int nblocks = 128 * 64;   // 8192 blocks x 256 threads (4 waves)
    conv7x7_mfma<<<nblocks, 256, 0, stream>>>(x, bws, out);
}

// Round 22
// 57.603 us; speedup vs baseline: 3.6308x; 3.6308x over previous
//
#include <hip/hip_runtime.h>

typedef short  bf16x8 __attribute__((ext_vector_type(8)));
typedef float  f32x4  __attribute__((ext_vector_type(4)));

#define WROWS 22            // 16 output rows + 6 halo
#define WSTR  72            // ushorts per row (144 B)
#define WPAD  8             // lane63/jo3 b128 overrun pad (zeroed, finite)
#define WSZ   (WROWS * WSTR + WPAD)   // 1592 ushorts
#define NCHW  18            // float4 chunks per row
#define CHTW  (WROWS * NCHW)          // 396 chunks per wave-tile
#define NTILE 8             // x-tiles per wave (full 512-col row band)

static __device__ __forceinline__ unsigned int rne16(float f) {
    unsigned int u = __float_as_uint(f);
    return (u + 0x7FFFu + ((u >> 16) & 1u)) >> 16;   // fp32 -> bf16 RNE
}

// ---- Setup: banded-B fragments once into ws (7 dy x 64 lanes x 16B) ----
// B[u][j] = w[dy][u-j-1]; rows u >= 23 structurally zero (kills A-read wrap).
__global__ void build_bfrag(const float* __restrict__ w, bf16x8* __restrict__ ws) {
    const int l   = threadIdx.x;      // 64 threads
    const int l15 = l & 15;
    const int u0  = (l >> 4) * 8;
#pragma unroll
    for (int dy = 0; dy < 7; ++dy) {
        union { unsigned int u[4]; bf16x8 v; } bb;
#pragma unroll
        for (int qp = 0; qp < 4; ++qp) {
            unsigned int half[2];
#pragma unroll
            for (int h = 0; h < 2; ++h) {
                const int d = u0 + qp * 2 + h - l15 - 1;     // weight col dx
                const float val = (d >= 0 && d < 7) ? w[dy * 7 + d] : 0.f;
                half[h] = rne16(val);
            }
            bb.u[qp] = half[0] | (half[1] << 16);
        }
        ws[dy * 64 + l] = bb.v;
    }
}

// ---- Main: barrier-free wave-private LDS; each wave marches 8 x-tiles
// across a 16-row band (A/B register ping-pong, ISSUE always 2 tiles ahead
// of its vmcnt wait -> ~1 tile of work covers each load's latency; cold
// stall paid once per 8 tiles). 1024 long-lived blocks = 4/CU, no churn. ----
__global__ __launch_bounds__(256)
void conv7x7_mfma(const float* __restrict__ x, const bf16x8* __restrict__ Bws,
                  float* __restrict__ out) {
    __shared__ unsigned short lds[4][WSZ];   // 12736 B/block

    const int W = 512, H = 512;
    // XCD-aware bijective swizzle (1024 % 8 == 0)
    const int raw = blockIdx.x;
    const int bi  = (raw & 7) * 128 + (raw >> 3);
    const int n   = bi >> 3;             // image
    const int by  = bi & 7;              // 64-row band

    const float* xn = x + (size_t)n * (H * W);
    float*       on = out + (size_t)n * (H * W);

    const int t   = threadIdx.x;
    const int l   = t & 63;
    const int wv  = t >> 6;
    const int l15 = l & 15;
    const int lk  = l >> 4;
    const int u0  = lk * 8;

    const int y0 = by * 64 + wv * 16;    // wave's output rows y0..y0+15

    unsigned short* my = lds[wv];        // wave-private region

    // Zero the pad (wave-private read-only wrap region)
    if (l < WPAD) my[WROWS * WSTR + l] = 0;

    // Prebuilt B fragments (L2-resident broadcast)
    bf16x8 Bf[7];
#pragma unroll
    for (int dy = 0; dy < 7; ++dy) Bf[dy] = Bws[dy * 64 + l];

    // k-invariant staging descriptors (7 chunks/lane per tile)
    int  d_roff[7], d_loff[7], d_xoff[7];
    bool d_rok[7], d_act[7];
#pragma unroll
    for (int it = 0; it < 7; ++it) {
        const int idx = l + 64 * it;
        const int r   = idx / NCHW;
        const int cc  = idx - r * NCHW;
        const int gr  = y0 - 3 + r;
        d_act[it]  = (idx < CHTW);
        d_rok[it]  = d_act[it] && (gr >= 0) && (gr < H);
        d_xoff[it] = -4 + 4 * cc;        // + 64*k at issue time
        d_roff[it] = gr * W;
        d_loff[it] = r * WSTR + 4 * cc;
    }

    float4 sregA[7], sregB[7];

#define ISSUE(SR, k_)                                                          \
    {                                                                          \
        _Pragma("unroll")                                                      \
        for (int it = 0; it < 7; ++it) {                                       \
            const int gc = d_xoff[it] + 64 * (k_);                             \
            float4 v = make_float4(0.f, 0.f, 0.f, 0.f);                        \
            if (d_rok[it] && gc >= 0 && gc <= W - 4)                           \
                v = *reinterpret_cast<const float4*>(&xn[d_roff[it] + gc]);    \
            SR[it] = v;                                                        \
        }                                                                      \
    }

#define LDSWRITE(SR)                                                           \
    {                                                                          \
        _Pragma("unroll")                                                      \
        for (int it = 0; it < 7; ++it) {                                       \
            if (d_act[it]) {                                                   \
                const unsigned p0 = rne16(SR[it].x) | (rne16(SR[it].y) << 16); \
                const unsigned p1 = rne16(SR[it].z) | (rne16(SR[it].w) << 16); \
                *reinterpret_cast<uint2*>(&my[d_loff[it]]) =                   \
                    make_uint2(p0, p1);                                        \
            }                                                                  \
        }                                                                      \
    }

#define COMPUTE(k_)                                                            \
    {                                                                          \
        const int xk = 64 * (k_);                                              \
        _Pragma("unroll")                                                      \
        for (int jo = 0; jo < 4; ++jo) {                                       \
            f32x4 acc = {0.f, 0.f, 0.f, 0.f};                                  \
            _Pragma("unroll")                                                  \
            for (int dy = 0; dy < 7; ++dy) {                                   \
                const int row = l15 + dy;                                      \
                const bf16x8 a = *reinterpret_cast<const bf16x8*>(             \
                    &my[row * WSTR + jo * 16 + u0]);                           \
                acc = __builtin_amdgcn_mfma_f32_16x16x32_bf16(a, Bf[dy], acc,  \
                                                              0, 0, 0);        \
            }                                                                  \
            _Pragma("unroll")                                                  \
            for (int rr = 0; rr < 4; ++rr) {                                   \
                const int gr = y0 + lk * 4 + rr;                               \
                on[(size_t)gr * W + xk + jo * 16 + l15] = acc[rr];             \
            }                                                                  \
        }                                                                      \
    }

    // March: ISSUE(k+2) sits one full tile of LDSWRITE+COMPUTE ahead of its
    // wait (counted vmcnt, no barriers anywhere). Same-wave in-order DS
    // makes buffer reuse safe without syncs.
    ISSUE(sregA, 0)
    ISSUE(sregB, 1)
#pragma unroll
    for (int kp = 0; kp < 4; ++kp) {
        LDSWRITE(sregA)
        COMPUTE(2 * kp)
        if (kp < 3) ISSUE(sregA, 2 * kp + 2)
        LDSWRITE(sregB)
        COMPUTE(2 * kp + 1)
        if (kp < 3) ISSUE(sregB, 2 * kp + 3)
    }

#undef ISSUE
#undef LDSWRITE
#undef COMPUTE
}

extern "C" void kernel_launch(void* const* d_in, const int* in_sizes, int n_in,
                              void* d_out, int out_size, void* d_ws, size_t ws_size,
                              hipStream_t stream) {
    const float* x = (const float*)d_in[0];
    const float* w = (const float*)d_in[1];
    float* out = (float*)d_out;
    bf16x8* bws = (bf16x8*)d_ws;

    build_bfrag<<<1, 64, 0, stream>>>(w, bws);

    const int nblocks = 128 * 8;   // 1024 blocks x 256 threads (4 waves)
    conv7x7_mfma<<<nblocks, 256, 0, stream>>>(x, bws, out);
}

// Round 23
// 52.663 us; speedup vs baseline: 3.9713x; 1.0938x over previous
//
#include <hip/hip_runtime.h>

typedef short  bf16x8 __attribute__((ext_vector_type(8)));
typedef float  f32x4  __attribute__((ext_vector_type(4)));

#define WROWS 22            // 16 output rows + 6 halo
#define WSTR  72            // ushorts per row (144 B)
#define WPAD  8             // lane63/jo3 b128 overrun pad (zeroed, finite)
#define WSZ   (WROWS * WSTR + WPAD)   // 1592 ushorts
#define NCHW  18            // float4 chunks per row
#define CHTW  (WROWS * NCHW)          // 396 chunks per wave-tile

static __device__ __forceinline__ unsigned int rne16(float f) {
    unsigned int u = __float_as_uint(f);
    return (u + 0x7FFFu + ((u >> 16) & 1u)) >> 16;   // fp32 -> bf16 RNE
}

// ---- Setup: banded weight fragments (7 dy x 64 lanes x 16B), UNCHANGED
// table: lane l, reg j holds w[dy][(l>>4)*8+j - (l&15) - 1] (0 if OOB).
// Used as MFMA **A-operand** now: A'[m=l15][u] = w[dy][u-m-1] -> same values
// because A and B fragment layouts are mutual transposes. ----
__global__ void build_bfrag(const float* __restrict__ w, bf16x8* __restrict__ ws) {
    const int l   = threadIdx.x;      // 64 threads
    const int l15 = l & 15;
    const int u0  = (l >> 4) * 8;
#pragma unroll
    for (int dy = 0; dy < 7; ++dy) {
        union { unsigned int u[4]; bf16x8 v; } bb;
#pragma unroll
        for (int qp = 0; qp < 4; ++qp) {
            unsigned int half[2];
#pragma unroll
            for (int h = 0; h < 2; ++h) {
                const int d = u0 + qp * 2 + h - l15 - 1;     // weight col dx
                const float val = (d >= 0 && d < 7) ? w[dy * 7 + d] : 0.f;
                half[h] = rne16(val);
            }
            bb.u[qp] = half[0] | (half[1] << 16);
        }
        ws[dy * 64 + l] = bb.v;
    }
}

// ---- Main: barrier-free wave-private LDS; 4-tile march per wave with a
// 3-deep staging ring (21 float4 in flight -> 3x Little's-law product).
// __launch_bounds__(256,3) grants the VGPR budget so the scheduler KEEPS
// the deep issue instead of flattening it (R17 showed VGPR=60 = sunk loads).
// Operand-swapped MFMA: D'[col][row] -> acc[0..3] = 4 consecutive output
// cols of one row -> float4 stores (4 vs 16 store issues per tile). ----
__global__ __launch_bounds__(256, 3)
void conv7x7_mfma(const float* __restrict__ x, const bf16x8* __restrict__ Bws,
                  float* __restrict__ out) {
    __shared__ unsigned short lds[4][WSZ];   // 12736 B/block

    const int W = 512, H = 512;
    // XCD-aware bijective swizzle (2048 % 8 == 0)
    const int raw = blockIdx.x;
    const int bi  = (raw & 7) * 256 + (raw >> 3);
    const int n   = bi >> 4;             // n(7) | ty(3) | g(1)
    const int ty  = (bi >> 1) & 7;
    const int g   = bi & 1;
    const int x0g = g * 256;             // 4 tiles: x0g + 64k

    const float* xn = x + (size_t)n * (H * W);
    float*       on = out + (size_t)n * (H * W);

    const int t   = threadIdx.x;
    const int l   = t & 63;
    const int wv  = t >> 6;
    const int l15 = l & 15;
    const int lk  = l >> 4;
    const int u0  = lk * 8;

    const int y0 = ty * 64 + wv * 16;    // wave's output rows y0..y0+15

    unsigned short* my = lds[wv];        // wave-private region

    // Zero the pad (wave-private read-only wrap region)
    if (l < WPAD) my[WROWS * WSTR + l] = 0;

    // Prebuilt banded weight fragments (L2-resident broadcast)
    bf16x8 Bf[7];
#pragma unroll
    for (int dy = 0; dy < 7; ++dy) Bf[dy] = Bws[dy * 64 + l];

    // k-invariant staging descriptors (7 chunks/lane per tile)
    int  d_roff[7], d_loff[7], d_xoff[7];
    bool d_rok[7], d_act[7];
#pragma unroll
    for (int it = 0; it < 7; ++it) {
        const int idx = l + 64 * it;
        const int r   = idx / NCHW;
        const int cc  = idx - r * NCHW;
        const int gr  = y0 - 3 + r;
        d_act[it]  = (idx < CHTW);
        d_rok[it]  = d_act[it] && (gr >= 0) && (gr < H);
        d_xoff[it] = x0g - 4 + 4 * cc;
        d_roff[it] = gr * W;
        d_loff[it] = r * WSTR + 4 * cc;
    }

    float4 sregA[7], sregB[7], sregC[7];

#define ISSUE(SR, k_)                                                          \
    {                                                                          \
        _Pragma("unroll")                                                      \
        for (int it = 0; it < 7; ++it) {                                       \
            const int gc = d_xoff[it] + 64 * (k_);                             \
            float4 v = make_float4(0.f, 0.f, 0.f, 0.f);                        \
            if (d_rok[it] && gc >= 0 && gc <= W - 4)                           \
                v = *reinterpret_cast<const float4*>(&xn[d_roff[it] + gc]);    \
            SR[it] = v;                                                        \
        }                                                                      \
    }

#define LDSWRITE(SR)                                                           \
    {                                                                          \
        _Pragma("unroll")                                                      \
        for (int it = 0; it < 7; ++it) {                                       \
            if (d_act[it]) {                                                   \
                const unsigned p0 = rne16(SR[it].x) | (rne16(SR[it].y) << 16); \
                const unsigned p1 = rne16(SR[it].z) | (rne16(SR[it].w) << 16); \
                *reinterpret_cast<uint2*>(&my[d_loff[it]]) =                   \
                    make_uint2(p0, p1);                                        \
            }                                                                  \
        }                                                                      \
    }

    // Operand-swapped compute + float4 store:
    // acc[rr] = out[row y0+l15][col xk + jo*16 + lk*4 + rr]
#define COMPUTE(k_)                                                            \
    {                                                                          \
        const int xk = x0g + 64 * (k_);                                        \
        _Pragma("unroll")                                                      \
        for (int jo = 0; jo < 4; ++jo) {                                       \
            f32x4 acc = {0.f, 0.f, 0.f, 0.f};                                  \
            _Pragma("unroll")                                                  \
            for (int dy = 0; dy < 7; ++dy) {                                   \
                const int row = l15 + dy;                                      \
                const bf16x8 a = *reinterpret_cast<const bf16x8*>(             \
                    &my[row * WSTR + jo * 16 + u0]);                           \
                acc = __builtin_amdgcn_mfma_f32_16x16x32_bf16(Bf[dy], a, acc,  \
                                                              0, 0, 0);        \
            }                                                                  \
            *reinterpret_cast<float4*>(                                        \
                &on[(size_t)(y0 + l15) * W + xk + jo * 16 + lk * 4]) =         \
                make_float4(acc[0], acc[1], acc[2], acc[3]);                   \
        }                                                                      \
    }

    // 3-deep ring: ISSUE stays 2-3 tiles ahead of its LDSWRITE wait.
    // Single LDS buffer is safe: same-wave DS ops execute in program order.
    ISSUE(sregA, 0)
    ISSUE(sregB, 1)
    ISSUE(sregC, 2)
    LDSWRITE(sregA)
    COMPUTE(0)
    ISSUE(sregA, 3)
    LDSWRITE(sregB)
    COMPUTE(1)
    LDSWRITE(sregC)
    COMPUTE(2)
    LDSWRITE(sregA)
    COMPUTE(3)

#undef ISSUE
#undef LDSWRITE
#undef COMPUTE
}

extern "C" void kernel_launch(void* const* d_in, const int* in_sizes, int n_in,
                              void* d_out, int out_size, void* d_ws, size_t ws_size,
                              hipStream_t stream) {
    const float* x = (const float*)d_in[0];
    const float* w = (const float*)d_in[1];
    float* out = (float*)d_out;
    bf16x8* bws = (bf16x8*)d_ws;

    build_bfrag<<<1, 64, 0, stream>>>(w, bws);

    const int nblocks = 128 * 8 * 2;   // 2048 blocks x 256 threads (4 waves)
    conv7x7_mfma<<<nblocks, 256, 0, stream>>>(x, bws, out);
}

// Round 24
// 50.794 us; speedup vs baseline: 4.1175x; 1.0368x over previous
//
#include <hip/hip_runtime.h>

typedef short  bf16x8 __attribute__((ext_vector_type(8)));
typedef float  f32x4  __attribute__((ext_vector_type(4)));

#define WROWS 22            // 16 output rows + 6 halo
#define WSTR  72            // ushorts per row (144 B)
#define WPAD  8             // lane63/jo3 b128 overrun pad (zeroed, finite)
#define WSZ   (WROWS * WSTR + WPAD)   // 1592 ushorts
#define NCHW  18            // float4 chunks per row
#define CHTW  (WROWS * NCHW)          // 396 chunks per wave-tile

static __device__ __forceinline__ unsigned int rne16(float f) {
    unsigned int u = __float_as_uint(f);
    return (u + 0x7FFFu + ((u >> 16) & 1u)) >> 16;   // fp32 -> bf16 RNE
}

// ---- Setup: banded weight fragments (7 dy x 64 lanes x 16B). Used as the
// MFMA A-operand (operand-swapped; R23 verified absmax 0.25): values are
// identical because A and B fragment layouts are mutual transposes. ----
__global__ void build_bfrag(const float* __restrict__ w, bf16x8* __restrict__ ws) {
    const int l   = threadIdx.x;      // 64 threads
    const int l15 = l & 15;
    const int u0  = (l >> 4) * 8;
#pragma unroll
    for (int dy = 0; dy < 7; ++dy) {
        union { unsigned int u[4]; bf16x8 v; } bb;
#pragma unroll
        for (int qp = 0; qp < 4; ++qp) {
            unsigned int half[2];
#pragma unroll
            for (int h = 0; h < 2; ++h) {
                const int d = u0 + qp * 2 + h - l15 - 1;     // weight col dx
                const float val = (d >= 0 && d < 7) ? w[dy * 7 + d] : 0.f;
                half[h] = rne16(val);
            }
            bb.u[qp] = half[0] | (half[1] << 16);
        }
        ws[dy * 64 + l] = bb.v;
    }
}

// ---- Main: EXACT R17 structure (champion, 48.5us) with ONE change:
// operand-swapped MFMA packs D as [col][row] -> acc[0..3] = 4 consecutive
// output cols of one row -> 4x dwordx4 stores/tile instead of 16x dword
// (4x fewer VMEM store slots competing with loads in the memory queue). ----
__global__ __launch_bounds__(256)
void conv7x7_mfma(const float* __restrict__ x, const bf16x8* __restrict__ Bws,
                  float* __restrict__ out) {
    __shared__ unsigned short lds[4][WSZ];   // 12736 B/block

    const int W = 512, H = 512;
    // XCD-aware bijective swizzle (4096 % 8 == 0)
    const int raw = blockIdx.x;
    const int bi  = (raw & 7) * 512 + (raw >> 3);
    const int n   = bi >> 5;             // n(7) | ty(3) | gx(2)
    const int ty  = (bi >> 2) & 7;
    const int gx  = bi & 3;

    const float* xn = x + (size_t)n * (H * W);
    float*       on = out + (size_t)n * (H * W);

    const int t   = threadIdx.x;
    const int l   = t & 63;
    const int wv  = t >> 6;
    const int l15 = l & 15;
    const int lk  = l >> 4;
    const int u0  = lk * 8;

    const int y0  = ty * 64 + wv * 16;   // wave's output rows y0..y0+15
    const int x0g = gx * 128;            // two tiles: x0g, x0g+64

    unsigned short* my = lds[wv];        // wave-private region

    // Zero the pad (wave-private read-only wrap region)
    if (l < WPAD) my[WROWS * WSTR + l] = 0;

    // Prebuilt banded weight fragments (L2-resident broadcast)
    bf16x8 Bf[7];
#pragma unroll
    for (int dy = 0; dy < 7; ++dy) Bf[dy] = Bws[dy * 64 + l];

    // k-invariant staging descriptors (7 chunks/lane per tile)
    int  d_roff[7], d_loff[7], d_xoff[7];
    bool d_rok[7], d_act[7];
#pragma unroll
    for (int it = 0; it < 7; ++it) {
        const int idx = l + 64 * it;
        const int r   = idx / NCHW;
        const int cc  = idx - r * NCHW;
        const int gr  = y0 - 3 + r;
        d_act[it]  = (idx < CHTW);
        d_rok[it]  = d_act[it] && (gr >= 0) && (gr < H);
        d_xoff[it] = x0g - 4 + 4 * cc;
        d_roff[it] = gr * W;
        d_loff[it] = r * WSTR + 4 * cc;
    }

    float4 sregA[7], sregB[7];

#define ISSUE(SR, k_)                                                          \
    {                                                                          \
        _Pragma("unroll")                                                      \
        for (int it = 0; it < 7; ++it) {                                       \
            const int gc = d_xoff[it] + 64 * (k_);                             \
            float4 v = make_float4(0.f, 0.f, 0.f, 0.f);                        \
            if (d_rok[it] && gc >= 0 && gc <= W - 4)                           \
                v = *reinterpret_cast<const float4*>(&xn[d_roff[it] + gc]);    \
            SR[it] = v;                                                        \
        }                                                                      \
    }

#define LDSWRITE(SR)                                                           \
    {                                                                          \
        _Pragma("unroll")                                                      \
        for (int it = 0; it < 7; ++it) {                                       \
            if (d_act[it]) {                                                   \
                const unsigned p0 = rne16(SR[it].x) | (rne16(SR[it].y) << 16); \
                const unsigned p1 = rne16(SR[it].z) | (rne16(SR[it].w) << 16); \
                *reinterpret_cast<uint2*>(&my[d_loff[it]]) =                   \
                    make_uint2(p0, p1);                                        \
            }                                                                  \
        }                                                                      \
    }

    // Swapped-operand compute: acc[rr] = out[y0+l15][xk + jo*16 + lk*4 + rr]
#define COMPUTE(k_)                                                            \
    {                                                                          \
        const int xk = x0g + 64 * (k_);                                        \
        float* orow = on + (size_t)(y0 + l15) * W + xk;                        \
        _Pragma("unroll")                                                      \
        for (int jo = 0; jo < 4; ++jo) {                                       \
            f32x4 acc = {0.f, 0.f, 0.f, 0.f};                                  \
            _Pragma("unroll")                                                  \
            for (int dy = 0; dy < 7; ++dy) {                                   \
                const int row = l15 + dy;                                      \
                const bf16x8 a = *reinterpret_cast<const bf16x8*>(             \
                    &my[row * WSTR + jo * 16 + u0]);                           \
                acc = __builtin_amdgcn_mfma_f32_16x16x32_bf16(Bf[dy], a, acc,  \
                                                              0, 0, 0);        \
            }                                                                  \
            *reinterpret_cast<float4*>(&orow[jo * 16 + lk * 4]) =              \
                make_float4(acc[0], acc[1], acc[2], acc[3]);                   \
        }                                                                      \
    }

    // R17 pipeline: both tiles' loads issued up front; counted vmcnt
    // (no barriers anywhere) lets tile-1 loads fly over write(0)+compute(0).
    ISSUE(sregA, 0)
    ISSUE(sregB, 1)
    LDSWRITE(sregA)
    COMPUTE(0)
    LDSWRITE(sregB)
    COMPUTE(1)

#undef ISSUE
#undef LDSWRITE
#undef COMPUTE
}

extern "C" void kernel_launch(void* const* d_in, const int* in_sizes, int n_in,
                              void* d_out, int out_size, void* d_ws, size_t ws_size,
                              hipStream_t stream) {
    const float* x = (const float*)d_in[0];
    const float* w = (const float*)d_in[1];
    float* out = (float*)d_out;
    bf16x8* bws = (bf16x8*)d_ws;

    build_bfrag<<<1, 64, 0, stream>>>(w, bws);

    const int nblocks = 128 * 8 * 4;   // 4096 blocks x 256 threads (4 waves)
    conv7x7_mfma<<<nblocks, 256, 0, stream>>>(x, bws, out);
}

// Round 25
// 49.826 us; speedup vs baseline: 4.1975x; 1.0194x over previous
//
#include <hip/hip_runtime.h>

typedef short  bf16x8 __attribute__((ext_vector_type(8)));
typedef float  f32x4  __attribute__((ext_vector_type(4)));

#define WROWS 22            // 16 output rows + 6 halo
#define WSTR  72            // ushorts per row (144 B)
#define WPAD  8             // lane63/jo3 b128 overrun pad (zeroed, finite)
#define WSZ   (WROWS * WSTR + WPAD)   // 1592 ushorts = 3184 B
#define NCHW  18            // float4 chunks per row
#define CHTW  (WROWS * NCHW)          // 396 chunks per wave-tile

static __device__ __forceinline__ unsigned int rne16(float f) {
    unsigned int u = __float_as_uint(f);
    return (u + 0x7FFFu + ((u >> 16) & 1u)) >> 16;   // fp32 -> bf16 RNE
}

// ---- Setup: banded-B fragments once into ws (7 dy x 64 lanes x 16B) ----
// B[u][j] = w[dy][u-j-1]; rows u >= 24 structurally zero (kills A-read wrap).
__global__ void build_bfrag(const float* __restrict__ w, bf16x8* __restrict__ ws) {
    const int l   = threadIdx.x;      // 64 threads
    const int l15 = l & 15;
    const int u0  = (l >> 4) * 8;
#pragma unroll
    for (int dy = 0; dy < 7; ++dy) {
        union { unsigned int u[4]; bf16x8 v; } bb;
#pragma unroll
        for (int qp = 0; qp < 4; ++qp) {
            unsigned int half[2];
#pragma unroll
            for (int h = 0; h < 2; ++h) {
                const int d = u0 + qp * 2 + h - l15 - 1;     // weight col dx
                const float val = (d >= 0 && d < 7) ? w[dy * 7 + d] : 0.f;
                half[h] = rne16(val);
            }
            bb.u[qp] = half[0] | (half[1] << 16);
        }
        ws[dy * 64 + l] = bb.v;
    }
}

// ---- Main: EXACT R17 champion structure, but ONE WAVE PER BLOCK.
// Kernel is fully wave-independent (no barriers, wave-private LDS), so
// 64-thread blocks let the CU scheduler pack waves individually
// (LDS 3184B/block -> 50 blocks/CU allowed; VGPR -> 8 waves/SIMD).
// Tests the low-residency hypothesis: R17 showed 33% occupancy with
// nothing visibly binding. ----
__global__ __launch_bounds__(64)
void conv7x7_mfma(const float* __restrict__ x, const bf16x8* __restrict__ Bws,
                  float* __restrict__ out) {
    __shared__ unsigned short my[WSZ];   // 3184 B/block (one wave)

    const int W = 512, H = 512;
    // XCD-aware bijective swizzle (16384 % 8 == 0)
    const int raw = blockIdx.x;
    const int bi  = (raw & 7) * 2048 + (raw >> 3);
    const int n   = bi >> 7;             // n(7) | ty(5) | gx(2)
    const int rem = bi & 127;
    const int ty  = rem >> 2;            // 0..31 (16-row band)
    const int gx  = rem & 3;

    const float* xn = x + (size_t)n * (H * W);
    float*       on = out + (size_t)n * (H * W);

    const int l   = threadIdx.x;         // 0..63
    const int l15 = l & 15;
    const int lk  = l >> 4;
    const int u0  = lk * 8;

    const int y0  = ty * 16;             // wave's output rows y0..y0+15
    const int x0g = gx * 128;            // two tiles: x0g, x0g+64

    // Zero the pad (wave-private read-only wrap region)
    if (l < WPAD) my[WROWS * WSTR + l] = 0;

    // Prebuilt B fragments (L2-resident broadcast)
    bf16x8 Bf[7];
#pragma unroll
    for (int dy = 0; dy < 7; ++dy) Bf[dy] = Bws[dy * 64 + l];

    // k-invariant staging descriptors (7 chunks/lane per tile)
    int  d_roff[7], d_loff[7], d_xoff[7];
    bool d_rok[7], d_act[7];
#pragma unroll
    for (int it = 0; it < 7; ++it) {
        const int idx = l + 64 * it;
        const int r   = idx / NCHW;
        const int cc  = idx - r * NCHW;
        const int gr  = y0 - 3 + r;
        d_act[it]  = (idx < CHTW);
        d_rok[it]  = d_act[it] && (gr >= 0) && (gr < H);
        d_xoff[it] = x0g - 4 + 4 * cc;
        d_roff[it] = gr * W;
        d_loff[it] = r * WSTR + 4 * cc;
    }

    float4 sregA[7], sregB[7];

#define ISSUE(SR, k_)                                                          \
    {                                                                          \
        _Pragma("unroll")                                                      \
        for (int it = 0; it < 7; ++it) {                                       \
            const int gc = d_xoff[it] + 64 * (k_);                             \
            float4 v = make_float4(0.f, 0.f, 0.f, 0.f);                        \
            if (d_rok[it] && gc >= 0 && gc <= W - 4)                           \
                v = *reinterpret_cast<const float4*>(&xn[d_roff[it] + gc]);    \
            SR[it] = v;                                                        \
        }                                                                      \
    }

#define LDSWRITE(SR)                                                           \
    {                                                                          \
        _Pragma("unroll")                                                      \
        for (int it = 0; it < 7; ++it) {                                       \
            if (d_act[it]) {                                                   \
                const unsigned p0 = rne16(SR[it].x) | (rne16(SR[it].y) << 16); \
                const unsigned p1 = rne16(SR[it].z) | (rne16(SR[it].w) << 16); \
                *reinterpret_cast<uint2*>(&my[d_loff[it]]) =                   \
                    make_uint2(p0, p1);                                        \
            }                                                                  \
        }                                                                      \
    }

#define COMPUTE(k_)                                                            \
    {                                                                          \
        const int xk = x0g + 64 * (k_);                                        \
        _Pragma("unroll")                                                      \
        for (int jo = 0; jo < 4; ++jo) {                                       \
            f32x4 acc = {0.f, 0.f, 0.f, 0.f};                                  \
            _Pragma("unroll")                                                  \
            for (int dy = 0; dy < 7; ++dy) {                                   \
                const int row = l15 + dy;                                      \
                const bf16x8 a = *reinterpret_cast<const bf16x8*>(             \
                    &my[row * WSTR + jo * 16 + u0]);                           \
                acc = __builtin_amdgcn_mfma_f32_16x16x32_bf16(a, Bf[dy], acc,  \
                                                              0, 0, 0);        \
            }                                                                  \
            _Pragma("unroll")                                                  \
            for (int rr = 0; rr < 4; ++rr) {                                   \
                const int gr = y0 + lk * 4 + rr;                               \
                on[(size_t)gr * W + xk + jo * 16 + l15] = acc[rr];             \
            }                                                                  \
        }                                                                      \
    }

    // R17 pipeline: both tiles' loads issued up front; counted vmcnt
    // (no barriers anywhere) lets tile-1 loads fly over write(0)+compute(0).
    ISSUE(sregA, 0)
    ISSUE(sregB, 1)
    LDSWRITE(sregA)
    COMPUTE(0)
    LDSWRITE(sregB)
    COMPUTE(1)

#undef ISSUE
#undef LDSWRITE
#undef COMPUTE
}

extern "C" void kernel_launch(void* const* d_in, const int* in_sizes, int n_in,
                              void* d_out, int out_size, void* d_ws, size_t ws_size,
                              hipStream_t stream) {
    const float* x = (const float*)d_in[0];
    const float* w = (const float*)d_in[1];
    float* out = (float*)d_out;
    bf16x8* bws = (bf16x8*)d_ws;

    build_bfrag<<<1, 64, 0, stream>>>(w, bws);

    const int nblocks = 128 * 32 * 4;   // 16384 blocks x 64 threads (1 wave)
    conv7x7_mfma<<<nblocks, 64, 0, stream>>>(x, bws, out);
}